// Round 3
// baseline (178.964 us; speedup 1.0000x reference)
//
#include <hip/hip_runtime.h>
#include <math.h>

#define KK 5
#define Bc 5.0f
#define NN 32768
#define DD 64
#define LL 63
#define PP 14
#define MIN_Wc 0.001f
#define MIN_Hc 0.001f
#define MIN_Dc 0.001f

typedef float f4 __attribute__((ext_vector_type(4)));
typedef const __attribute__((address_space(1))) float g_float;
typedef const __attribute__((address_space(1))) f4    g_f4;

// Force a (uniform) pointer through VGPRs so subsequent loads compile to
// global_load (vmcnt, in-order, pipelinable) instead of s_load (lgkmcnt,
// out-of-order -> forces lgkmcnt(0) drains that also stall ds_read).
__device__ __forceinline__ unsigned long long vgpr_addr(const void* p) {
    unsigned long long u = (unsigned long long)p;
    unsigned int lo = (unsigned int)u, hi = (unsigned int)(u >> 32);
    unsigned int vlo, vhi;
    asm("v_mov_b32 %0, %2\n\tv_mov_b32 %1, %3"
        : "=v"(vlo), "=v"(vhi) : "s"(lo), "s"(hi));
    return ((unsigned long long)vhi << 32) | (unsigned long long)vlo;
}

__device__ __forceinline__ float rcp_fast(float v)  { return __builtin_amdgcn_rcpf(v); }
__device__ __forceinline__ float exp_fast(float v)  { return __expf(v); }
__device__ __forceinline__ float log_fast(float v)  { return __logf(v); }
__device__ __forceinline__ float tanh_fast(float v) {
    float e = exp_fast(2.0f * v);                 // overflow->inf->rcp->0->1: correct
    return 1.0f - 2.0f * rcp_fast(e + 1.0f);
}
__device__ __forceinline__ float softplus_fast(float v) {
    return (v > 15.0f) ? v : log_fast(1.0f + exp_fast(v));
}

__global__ __launch_bounds__(256) void nsf_kernel(
    const float* __restrict__ x, const float* __restrict__ init_param,
    const float* __restrict__ W1, const float* __restrict__ b1,
    const float* __restrict__ W2, const float* __restrict__ b2,
    const float* __restrict__ W3, const float* __restrict__ b3,
    float* __restrict__ out)
{
    // chunk-major x tile: xs[jc][sample] as f4 -> ds_read_b128 is exactly
    // 2 words/bank per phase (free 2-way), ds_write_b128 likewise.
    __shared__ f4 xs[16 * 64];
    const int s0 = blockIdx.x * 64;
    const int tid = threadIdx.x;
    const int lane = tid & 63;
    const int wave = tid >> 6;

    {   // stage: wave w loads chunks {w, w+4, w+8, w+12}, lane = sample
        const f4* xg = (const f4*)(x + s0 * 64);
        #pragma unroll
        for (int it = 0; it < 4; ++it) {
            int jc = wave + it * 4;
            xs[jc * 64 + lane] = xg[lane * 16 + jc];
        }
    }
    __syncthreads();

    g_float* ipv = (g_float*)vgpr_addr(init_param);
    g_f4*    W1v = (g_f4*)vgpr_addr(W1);
    g_f4*    b1v = (g_f4*)vgpr_addr(b1);
    g_f4*    W2v = (g_f4*)vgpr_addr(W2);
    g_f4*    b2v = (g_f4*)vgpr_addr(b2);
    g_f4*    W3v = (g_f4*)vgpr_addr(W3);
    g_float* b3v = (g_float*)vgpr_addr(b3);

    const int t = blockIdx.y * 4 + wave;   // 0..15, wave-uniform

    #pragma unroll 1
    for (int k = 0; k < 4; ++k) {
        // balanced dim set {t, 31-t, 32+t, 63-t}: layer-1 trips sum to 126/wave
        int dd;
        switch (k) {
            case 0: dd = t;       break;
            case 1: dd = 31 - t;  break;
            case 2: dd = 32 + t;  break;
            default: dd = 63 - t; break;
        }
        dd = __builtin_amdgcn_readfirstlane(dd);  // keep index math scalar

        float p[PP];
        if (dd == 0) {
            #pragma unroll
            for (int i = 0; i < PP; ++i) p[i] = ipv[i];
        } else {
            const int l = dd - 1;

            // ---- layer 1: h1 = tanh(sum_{j<=l} x[j]*W1[l,j,:] + b1[l,:]) ----
            f4 bb0 = b1v[l * 2], bb1 = b1v[l * 2 + 1];
            float h1[8] = {bb0.x, bb0.y, bb0.z, bb0.w, bb1.x, bb1.y, bb1.z, bb1.w};
            g_f4* w1p = W1v + l * 126;          // l*504 floats / 4
            const f4* xcv = xs + lane;
            const int nfull = l >> 2;
            for (int jc = 0; jc < nfull; ++jc) {
                f4 xv = xcv[jc * 64];           // ds_read_b128, 4 j's
                f4 wA = w1p[0], wB = w1p[1], wC = w1p[2], wD = w1p[3];
                f4 wE = w1p[4], wF = w1p[5], wG = w1p[6], wH = w1p[7];
                w1p += 8;
                h1[0]=fmaf(xv.x,wA.x,h1[0]); h1[1]=fmaf(xv.x,wA.y,h1[1]);
                h1[2]=fmaf(xv.x,wA.z,h1[2]); h1[3]=fmaf(xv.x,wA.w,h1[3]);
                h1[4]=fmaf(xv.x,wB.x,h1[4]); h1[5]=fmaf(xv.x,wB.y,h1[5]);
                h1[6]=fmaf(xv.x,wB.z,h1[6]); h1[7]=fmaf(xv.x,wB.w,h1[7]);
                h1[0]=fmaf(xv.y,wC.x,h1[0]); h1[1]=fmaf(xv.y,wC.y,h1[1]);
                h1[2]=fmaf(xv.y,wC.z,h1[2]); h1[3]=fmaf(xv.y,wC.w,h1[3]);
                h1[4]=fmaf(xv.y,wD.x,h1[4]); h1[5]=fmaf(xv.y,wD.y,h1[5]);
                h1[6]=fmaf(xv.y,wD.z,h1[6]); h1[7]=fmaf(xv.y,wD.w,h1[7]);
                h1[0]=fmaf(xv.z,wE.x,h1[0]); h1[1]=fmaf(xv.z,wE.y,h1[1]);
                h1[2]=fmaf(xv.z,wE.z,h1[2]); h1[3]=fmaf(xv.z,wE.w,h1[3]);
                h1[4]=fmaf(xv.z,wF.x,h1[4]); h1[5]=fmaf(xv.z,wF.y,h1[5]);
                h1[6]=fmaf(xv.z,wF.z,h1[6]); h1[7]=fmaf(xv.z,wF.w,h1[7]);
                h1[0]=fmaf(xv.w,wG.x,h1[0]); h1[1]=fmaf(xv.w,wG.y,h1[1]);
                h1[2]=fmaf(xv.w,wG.z,h1[2]); h1[3]=fmaf(xv.w,wG.w,h1[3]);
                h1[4]=fmaf(xv.w,wH.x,h1[4]); h1[5]=fmaf(xv.w,wH.y,h1[5]);
                h1[6]=fmaf(xv.w,wH.z,h1[6]); h1[7]=fmaf(xv.w,wH.w,h1[7]);
            }
            {   // tail: j = 4*nfull .. l (1..4 elems, wave-uniform trip)
                f4 xv = xcv[nfull * 64];
                float xt[4] = {xv.x, xv.y, xv.z, xv.w};
                const int rem = l & 3;
                #pragma unroll
                for (int i = 0; i < 4; ++i) {
                    if (i <= rem) {
                        f4 wa = w1p[2 * i], wb = w1p[2 * i + 1];
                        h1[0]=fmaf(xt[i],wa.x,h1[0]); h1[1]=fmaf(xt[i],wa.y,h1[1]);
                        h1[2]=fmaf(xt[i],wa.z,h1[2]); h1[3]=fmaf(xt[i],wa.w,h1[3]);
                        h1[4]=fmaf(xt[i],wb.x,h1[4]); h1[5]=fmaf(xt[i],wb.y,h1[5]);
                        h1[6]=fmaf(xt[i],wb.z,h1[6]); h1[7]=fmaf(xt[i],wb.w,h1[7]);
                    }
                }
            }
            #pragma unroll
            for (int h = 0; h < 8; ++h) h1[h] = tanh_fast(h1[h]);

            // ---- layer 2 ----
            f4 cb0 = b2v[l * 2], cb1 = b2v[l * 2 + 1];
            float h2[8] = {cb0.x, cb0.y, cb0.z, cb0.w, cb1.x, cb1.y, cb1.z, cb1.w};
            g_f4* w2p = W2v + l * 16;
            #pragma unroll
            for (int m = 0; m < 16; ++m) {
                f4 w = w2p[m];
                float hv = h1[m >> 1];
                int g0 = (m & 1) * 4;
                h2[g0+0] = fmaf(hv, w.x, h2[g0+0]);
                h2[g0+1] = fmaf(hv, w.y, h2[g0+1]);
                h2[g0+2] = fmaf(hv, w.z, h2[g0+2]);
                h2[g0+3] = fmaf(hv, w.w, h2[g0+3]);
            }
            #pragma unroll
            for (int g = 0; g < 8; ++g) h2[g] = tanh_fast(h2[g]);

            // ---- layer 3 ----
            g_float* b3l = b3v + l * PP;
            #pragma unroll
            for (int q = 0; q < PP; ++q) p[q] = b3l[q];
            g_f4* w3p = W3v + l * 28;
            #pragma unroll
            for (int m = 0; m < 28; ++m) {
                f4 w = w3p[m];
                #pragma unroll
                for (int i2 = 0; i2 < 4; ++i2) {
                    int f = 4 * m + i2;
                    float wv = (i2 == 0) ? w.x : (i2 == 1) ? w.y : (i2 == 2) ? w.z : w.w;
                    p[f % PP] = fmaf(h2[f / PP], wv, p[f % PP]);
                }
            }
        }

        // ---- rational quadratic spline ----
        const float xf = ((const float*)(xs + ((dd >> 2) * 64 + lane)))[dd & 3];

        // softmax without max-subtraction (|p| small; exp safe, saves dep chain)
        float we[KK]; float wsum = 0.f;
        #pragma unroll
        for (int i = 0; i < KK; ++i) { we[i] = exp_fast(p[i]); wsum += we[i]; }
        const float wnorm = (1.0f - MIN_Wc * KK) * rcp_fast(wsum);
        float cumw[KK + 1], wdt[KK];
        cumw[0] = -Bc;
        float acw = 0.f;
        #pragma unroll
        for (int i = 0; i < KK; ++i) { acw += MIN_Wc + wnorm * we[i]; cumw[i + 1] = 2.f * Bc * acw - Bc; }
        cumw[KK] = Bc;
        #pragma unroll
        for (int i = 0; i < KK; ++i) wdt[i] = cumw[i + 1] - cumw[i];

        float he[KK]; float hsum = 0.f;
        #pragma unroll
        for (int i = 0; i < KK; ++i) { he[i] = exp_fast(p[KK + i]); hsum += he[i]; }
        const float hnorm = (1.0f - MIN_Hc * KK) * rcp_fast(hsum);
        float cumh[KK + 1], hgt[KK];
        cumh[0] = -Bc;
        float ach = 0.f;
        #pragma unroll
        for (int i = 0; i < KK; ++i) { ach += MIN_Hc + hnorm * he[i]; cumh[i + 1] = 2.f * Bc * ach - Bc; }
        cumh[KK] = Bc;
        #pragma unroll
        for (int i = 0; i < KK; ++i) hgt[i] = cumh[i + 1] - cumh[i];

        float derivs[KK + 1];
        derivs[0] = 1.0f;
        derivs[KK] = 1.0f;
        #pragma unroll
        for (int i = 0; i < KK - 1; ++i) derivs[i + 1] = MIN_Dc + softplus_fast(p[2 * KK + i]);

        const float xc = fminf(fmaxf(xf, -Bc), Bc);

        float icw = cumw[0], ibw = wdt[0], ich = cumh[0], ih = hgt[0];
        float idv = derivs[0], idvp1 = derivs[1];
        #pragma unroll
        for (int i = 1; i < KK; ++i) {
            bool c = xc >= cumw[i];
            icw   = c ? cumw[i]       : icw;
            ibw   = c ? wdt[i]        : ibw;
            ich   = c ? cumh[i]       : ich;
            ih    = c ? hgt[i]        : ih;
            idv   = c ? derivs[i]     : idv;
            idvp1 = c ? derivs[i + 1] : idvp1;
        }

        const float ibw_r = rcp_fast(ibw);
        const float idl = ih * ibw_r;
        const float theta = (xc - icw) * ibw_r;
        const float omt = 1.0f - theta;
        const float tmt = theta * omt;
        const float num = ih * (idl * theta * theta + idv * tmt);
        const float den = idl + (idv + idvp1 - 2.0f * idl) * tmt;
        const float outv = ich + num * rcp_fast(den);
        const float dnum = idl * idl * (idvp1 * theta * theta + 2.0f * idl * tmt + idv * omt * omt);
        const float ld = log_fast(dnum) - 2.0f * log_fast(den);

        const bool inside = (xf >= -Bc) && (xf <= Bc);
        const float z = inside ? outv : xf;
        float ldv = inside ? ld : 0.0f;

        out[dd * NN + s0 + lane] = z;   // coalesced

        #pragma unroll
        for (int off = 32; off > 0; off >>= 1) ldv += __shfl_down(ldv, off);
        if (lane == 0) out[NN * DD + dd * (NN / 64) + blockIdx.x] = ldv;
    }
}

extern "C" void kernel_launch(void* const* d_in, const int* in_sizes, int n_in,
                              void* d_out, int out_size, void* d_ws, size_t ws_size,
                              hipStream_t stream) {
    const float* x          = (const float*)d_in[0];
    const float* init_param = (const float*)d_in[1];
    const float* W1         = (const float*)d_in[2];
    const float* b1         = (const float*)d_in[3];
    const float* W2         = (const float*)d_in[4];
    const float* b2         = (const float*)d_in[5];
    const float* W3         = (const float*)d_in[6];
    const float* b3         = (const float*)d_in[7];
    float* out = (float*)d_out;

    dim3 grid(NN / 64, 4);
    nsf_kernel<<<grid, 256, 0, stream>>>(x, init_param, W1, b1, W2, b2, W3, b3, out);
}

// Round 4
// 122.752 us; speedup vs baseline: 1.4579x; 1.4579x over previous
//
#include <hip/hip_runtime.h>
#include <hip/hip_bf16.h>
#include <math.h>

#define KK 5
#define Bc 5.0f
#define NN 32768
#define DD 64
#define LL 63
#define PP 14
#define MIN_Wc 0.001f
#define MIN_Hc 0.001f
#define MIN_Dc 0.001f

typedef float f4 __attribute__((ext_vector_type(4)));
typedef float f32x4 __attribute__((ext_vector_type(4)));
typedef short short8 __attribute__((ext_vector_type(8)));

__device__ __forceinline__ float rcp_fast(float v)  { return __builtin_amdgcn_rcpf(v); }
__device__ __forceinline__ float exp_fast(float v)  { return __expf(v); }
__device__ __forceinline__ float log_fast(float v)  { return __logf(v); }
__device__ __forceinline__ float tanh_fast(float v) {
    float e = exp_fast(2.0f * v);                 // overflow->inf->rcp->0->1: correct
    return 1.0f - 2.0f * rcp_fast(e + 1.0f);
}
__device__ __forceinline__ float softplus_fast(float v) {
    return (v > 15.0f) ? v : log_fast(1.0f + exp_fast(v));
}
__device__ __forceinline__ ushort to_bf16u(float v) {
    __hip_bfloat16 b = __float2bfloat16(v);
    return *(ushort*)&b;
}

// ---------------- kernel 0: pack W1 fp32 -> bf16 B[512][64] (n-major) -------
// B[n][k] = W1[l=n>>3, j=k, h=n&7] for n<504,k<63 else 0. W1 arrives pre-masked.
__global__ __launch_bounds__(256) void pack_b1(const float* __restrict__ W1,
                                               ushort* __restrict__ Bp) {
    int id = blockIdx.x * 256 + threadIdx.x;     // 0..32767
    int n = id >> 6, k = id & 63;
    float v = 0.f;
    if (n < 504 && k < 63) {
        int l = n >> 3, h = n & 7;
        v = W1[(l * 63 + k) * 8 + h];
    }
    Bp[id] = to_bf16u(v);
}

// ---------------- kernel 1: h1 = tanh(x @ B + b1), MFMA bf16 ----------------
// h1 stored bf16 as [l][n][8]  (coalesced 16B/lane reads in kernel 2)
#define AS 72   // LDS row stride in bf16 (64 + 8 pad -> 2-way-max bank aliasing)
__global__ __launch_bounds__(256) void mlp1_kernel(
    const float* __restrict__ x, const ushort* __restrict__ Bp,
    const float* __restrict__ b1, ushort* __restrict__ h1out)
{
    __shared__ ushort Alds[64 * AS];   // 64 samples x 64 k
    __shared__ ushort Blds[128 * AS];  // 128 n x 64 k
    const int tid = threadIdx.x;
    const int row0 = blockIdx.x * 64;       // sample base
    const int nbase = blockIdx.y * 128;     // output-col base

    // stage A: x tile fp32 -> bf16  (thread: row tid>>2, 16 cols)
    {
        int r = tid >> 2, c4 = (tid & 3) * 16;
        const f4* xg = (const f4*)(x + (size_t)(row0 + r) * 64 + c4);
        #pragma unroll
        for (int i = 0; i < 4; ++i) {
            f4 v = xg[i];
            ushort4 u;
            u.x = to_bf16u(v.x); u.y = to_bf16u(v.y);
            u.z = to_bf16u(v.z); u.w = to_bf16u(v.w);
            *(ushort4*)(&Alds[r * AS + c4 + i * 4]) = u;
        }
    }
    // stage B slice: rows [nbase, nbase+128) x 64, bf16, contiguous in global
    {
        const short8* src = (const short8*)(Bp + (size_t)nbase * 64);
        #pragma unroll
        for (int i = 0; i < 4; ++i) {
            int e = tid * 4 + i;            // 16B chunk id, 0..1023
            int n = e >> 3, kc = (e & 7) * 8;
            *(short8*)(&Blds[n * AS + kc]) = src[e];
        }
    }
    __syncthreads();

    const int lane = tid & 63, wave = tid >> 6;
    const int m0 = wave * 16;               // wave's row base within tile
    const int qg = lane >> 4;               // quad-group 0..3
    const int ln = lane & 15;

    // A-frags for both k-steps, reused across all 8 n-tiles
    short8 a0 = *(const short8*)(&Alds[(m0 + ln) * AS + qg * 8]);
    short8 a1 = *(const short8*)(&Alds[(m0 + ln) * AS + 32 + qg * 8]);

    #pragma unroll
    for (int t = 0; t < 8; ++t) {
        short8 bf0 = *(const short8*)(&Blds[(t * 16 + ln) * AS + qg * 8]);
        short8 bf1 = *(const short8*)(&Blds[(t * 16 + ln) * AS + 32 + qg * 8]);
        f32x4 acc = {0.f, 0.f, 0.f, 0.f};
        acc = __builtin_amdgcn_mfma_f32_16x16x32_bf16(a0, bf0, acc, 0, 0, 0);
        acc = __builtin_amdgcn_mfma_f32_16x16x32_bf16(a1, bf1, acc, 0, 0, 0);

        int ng = nbase + t * 16 + ln;       // global output col = l*8+h
        bool valid = ng < 504;
        float bias = valid ? b1[ng] : 0.f;  // b1 flat is exactly [l*8+h]
        int l = ng >> 3, h = ng & 7;
        ushort* dst = h1out + ((size_t)l * NN + row0 + m0 + qg * 4) * 8 + h;
        #pragma unroll
        for (int r = 0; r < 4; ++r) {
            float v = tanh_fast(acc[r] + bias);
            if (valid) dst[r * 8] = to_bf16u(v);
        }
    }
}

// ---------------- kernel 2: layers 2,3 + RQS spline -------------------------
__global__ __launch_bounds__(256) void spline_kernel(
    const float* __restrict__ x, const float* __restrict__ init_param,
    const ushort* __restrict__ h1g,
    const float* __restrict__ W2, const float* __restrict__ b2,
    const float* __restrict__ W3, const float* __restrict__ b3,
    float* __restrict__ out)
{
    __shared__ float xs[64 * 65];
    const int s0 = blockIdx.x * 64;
    const int tid = threadIdx.x;
    for (int q = tid; q < 64 * 64; q += 256) {
        int r = q >> 6, c = q & 63;
        xs[r * 65 + c] = x[(size_t)(s0 + r) * 64 + c];
    }
    __syncthreads();

    const int lane = tid & 63, wave = tid >> 6;
    const int t = blockIdx.y * 4 + wave;    // 0..15, wave-uniform

    #pragma unroll 1
    for (int kk = 0; kk < 4; ++kk) {
        int dd = __builtin_amdgcn_readfirstlane(t + kk * 16);  // 0..63, uniform

        float p[PP];
        if (dd == 0) {
            #pragma unroll
            for (int i = 0; i < PP; ++i) p[i] = init_param[i];
        } else {
            const int l = dd - 1;
            // h1: one coalesced 16B load per lane
            const uint4* hp = (const uint4*)(h1g + (size_t)l * NN * 8);
            uint4 hv = hp[s0 + lane];
            float h1f[8];
            h1f[0] = __uint_as_float(hv.x << 16);
            h1f[1] = __uint_as_float(hv.x & 0xFFFF0000u);
            h1f[2] = __uint_as_float(hv.y << 16);
            h1f[3] = __uint_as_float(hv.y & 0xFFFF0000u);
            h1f[4] = __uint_as_float(hv.z << 16);
            h1f[5] = __uint_as_float(hv.z & 0xFFFF0000u);
            h1f[6] = __uint_as_float(hv.w << 16);
            h1f[7] = __uint_as_float(hv.w & 0xFFFF0000u);

            float h2[8];
            #pragma unroll
            for (int g = 0; g < 8; ++g) h2[g] = b2[l * 8 + g];
            #pragma unroll
            for (int h = 0; h < 8; ++h) {
                #pragma unroll
                for (int g = 0; g < 8; ++g)
                    h2[g] = fmaf(h1f[h], W2[l * 64 + h * 8 + g], h2[g]);
            }
            #pragma unroll
            for (int g = 0; g < 8; ++g) h2[g] = tanh_fast(h2[g]);

            #pragma unroll
            for (int q = 0; q < PP; ++q) p[q] = b3[l * PP + q];
            #pragma unroll
            for (int g = 0; g < 8; ++g) {
                #pragma unroll
                for (int q = 0; q < PP; ++q)
                    p[q] = fmaf(h2[g], W3[(l * 8 + g) * PP + q], p[q]);
            }
        }

        // ---- rational quadratic spline (round-2 proven) ----
        const float xf = xs[lane * 65 + dd];

        float wmax = p[0];
        #pragma unroll
        for (int i = 1; i < KK; ++i) wmax = fmaxf(wmax, p[i]);
        float we[KK]; float wsum = 0.f;
        #pragma unroll
        for (int i = 0; i < KK; ++i) { we[i] = exp_fast(p[i] - wmax); wsum += we[i]; }
        const float wnorm = (1.0f - MIN_Wc * KK) * rcp_fast(wsum);
        float cumw[KK + 1], wdt[KK];
        cumw[0] = -Bc;
        float acw = 0.f;
        #pragma unroll
        for (int i = 0; i < KK; ++i) { acw += MIN_Wc + wnorm * we[i]; cumw[i + 1] = 2.f * Bc * acw - Bc; }
        cumw[KK] = Bc;
        #pragma unroll
        for (int i = 0; i < KK; ++i) wdt[i] = cumw[i + 1] - cumw[i];

        float hmax = p[KK];
        #pragma unroll
        for (int i = 1; i < KK; ++i) hmax = fmaxf(hmax, p[KK + i]);
        float he[KK]; float hsum = 0.f;
        #pragma unroll
        for (int i = 0; i < KK; ++i) { he[i] = exp_fast(p[KK + i] - hmax); hsum += he[i]; }
        const float hnorm = (1.0f - MIN_Hc * KK) * rcp_fast(hsum);
        float cumh[KK + 1], hgt[KK];
        cumh[0] = -Bc;
        float ach = 0.f;
        #pragma unroll
        for (int i = 0; i < KK; ++i) { ach += MIN_Hc + hnorm * he[i]; cumh[i + 1] = 2.f * Bc * ach - Bc; }
        cumh[KK] = Bc;
        #pragma unroll
        for (int i = 0; i < KK; ++i) hgt[i] = cumh[i + 1] - cumh[i];

        float derivs[KK + 1];
        derivs[0] = 1.0f;
        derivs[KK] = 1.0f;
        #pragma unroll
        for (int i = 0; i < KK - 1; ++i) derivs[i + 1] = MIN_Dc + softplus_fast(p[2 * KK + i]);

        const float xc = fminf(fmaxf(xf, -Bc), Bc);

        float icw = cumw[0], ibw = wdt[0], ich = cumh[0], ih = hgt[0];
        float idv = derivs[0], idvp1 = derivs[1];
        #pragma unroll
        for (int i = 1; i < KK; ++i) {
            bool c = xc >= cumw[i];
            icw   = c ? cumw[i]       : icw;
            ibw   = c ? wdt[i]        : ibw;
            ich   = c ? cumh[i]       : ich;
            ih    = c ? hgt[i]        : ih;
            idv   = c ? derivs[i]     : idv;
            idvp1 = c ? derivs[i + 1] : idvp1;
        }

        const float ibw_r = rcp_fast(ibw);
        const float idl = ih * ibw_r;
        const float theta = (xc - icw) * ibw_r;
        const float omt = 1.0f - theta;
        const float tmt = theta * omt;
        const float num = ih * (idl * theta * theta + idv * tmt);
        const float den = idl + (idv + idvp1 - 2.0f * idl) * tmt;
        const float outv = ich + num * rcp_fast(den);
        const float dnum = idl * idl * (idvp1 * theta * theta + 2.0f * idl * tmt + idv * omt * omt);
        const float ld = log_fast(dnum) - 2.0f * log_fast(den);

        const bool inside = (xf >= -Bc) && (xf <= Bc);
        const float z = inside ? outv : xf;
        float ldv = inside ? ld : 0.0f;

        out[dd * NN + s0 + lane] = z;   // coalesced

        #pragma unroll
        for (int off = 32; off > 0; off >>= 1) ldv += __shfl_down(ldv, off);
        if (lane == 0) out[NN * DD + dd * (NN / 64) + blockIdx.x] = ldv;
    }
}

extern "C" void kernel_launch(void* const* d_in, const int* in_sizes, int n_in,
                              void* d_out, int out_size, void* d_ws, size_t ws_size,
                              hipStream_t stream) {
    const float* x          = (const float*)d_in[0];
    const float* init_param = (const float*)d_in[1];
    const float* W1         = (const float*)d_in[2];
    const float* b1         = (const float*)d_in[3];
    const float* W2         = (const float*)d_in[4];
    const float* b2         = (const float*)d_in[5];
    const float* W3         = (const float*)d_in[6];
    const float* b3         = (const float*)d_in[7];
    float* out = (float*)d_out;

    ushort* Bp = (ushort*)d_ws;                  // 512*64 bf16 = 64 KB
    ushort* h1 = (ushort*)d_ws + 512 * 64;       // 63*32768*8 bf16 = 33 MB

    pack_b1<<<128, 256, 0, stream>>>(W1, Bp);
    mlp1_kernel<<<dim3(512, 4), 256, 0, stream>>>(x, Bp, b1, h1);
    spline_kernel<<<dim3(512, 4), 256, 0, stream>>>(x, init_param, h1,
                                                    W2, b2, W3, b3, out);
}

// Round 5
// 117.118 us; speedup vs baseline: 1.5281x; 1.0481x over previous
//
#include <hip/hip_runtime.h>
#include <hip/hip_bf16.h>
#include <math.h>

#define KK 5
#define Bc 5.0f
#define NN 32768
#define DD 64
#define LL 63
#define PP 14
#define MIN_Wc 0.001f
#define MIN_Hc 0.001f
#define MIN_Dc 0.001f

typedef float f4 __attribute__((ext_vector_type(4)));
typedef float f32x4 __attribute__((ext_vector_type(4)));
typedef short short8 __attribute__((ext_vector_type(8)));

__device__ __forceinline__ float rcp_fast(float v)  { return __builtin_amdgcn_rcpf(v); }
__device__ __forceinline__ float exp_fast(float v)  { return __expf(v); }
__device__ __forceinline__ float log_fast(float v)  { return __logf(v); }
__device__ __forceinline__ float tanh_fast(float v) {
    float e = exp_fast(2.0f * v);                 // overflow->inf->rcp->0->1: correct
    return 1.0f - 2.0f * rcp_fast(e + 1.0f);
}
__device__ __forceinline__ float softplus_fast(float v) {
    return (v > 15.0f) ? v : log_fast(1.0f + exp_fast(v));
}
__device__ __forceinline__ ushort to_bf16u(float v) {
    __hip_bfloat16 b = __float2bfloat16(v);
    return *(ushort*)&b;
}

// ---------------- kernel 0: pack W1 fp32 -> bf16 B[512][64] (n-major) -------
// B[n][k] = W1[l=n>>3, j=k, h=n&7] for n<504,k<63 else 0. W1 arrives pre-masked.
__global__ __launch_bounds__(256) void pack_b1(const float* __restrict__ W1,
                                               ushort* __restrict__ Bp) {
    int id = blockIdx.x * 256 + threadIdx.x;     // 0..32767
    int n = id >> 6, k = id & 63;
    float v = 0.f;
    if (n < 504 && k < 63) {
        int l = n >> 3, h = n & 7;
        v = W1[(l * 63 + k) * 8 + h];
    }
    Bp[id] = to_bf16u(v);
}

__device__ __forceinline__ short8 pack_a(f4 v0, f4 v1) {
    short8 a;
    a[0] = (short)to_bf16u(v0.x); a[1] = (short)to_bf16u(v0.y);
    a[2] = (short)to_bf16u(v0.z); a[3] = (short)to_bf16u(v0.w);
    a[4] = (short)to_bf16u(v1.x); a[5] = (short)to_bf16u(v1.y);
    a[6] = (short)to_bf16u(v1.z); a[7] = (short)to_bf16u(v1.w);
    return a;
}

// ---------------- fused kernel: MFMA layer-1 (LDS-resident h1) + layers 2,3 + spline
// grid (512, 2): x = 64-sample tile, y = dim-half. y0: dims 1..32 (l<32 -> k<32
// suffices, W1 pre-masked). y1: dims 33..63 + dim 0 (init_param).
__global__ __launch_bounds__(256) void fused_kernel(
    const float* __restrict__ x, const float* __restrict__ init_param,
    const ushort* __restrict__ Bp, const float* __restrict__ b1,
    const float* __restrict__ W2, const float* __restrict__ b2,
    const float* __restrict__ W3, const float* __restrict__ b3,
    float* __restrict__ out)
{
    __shared__ float xs[64 * 65];          // fp32 x tile (spline xf), conflict-free
    __shared__ ushort h1c[2][64 * 72];     // double-buffered bf16 h1 chunk [sample][outcol]
    const int tid = threadIdx.x;
    const int s0 = blockIdx.x * 64;
    const int y  = blockIdx.y;

    for (int q = tid; q < 64 * 64; q += 256) {
        int r = q >> 6, c = q & 63;
        xs[r * 65 + c] = x[(size_t)(s0 + r) * 64 + c];
    }

    const int lane = tid & 63, wave = tid >> 6;
    const int ln = lane & 15, qg = lane >> 4;
    const int m0 = wave * 16;              // wave's MFMA m-tile (samples)

    // A-fragments from global (L1-resident tile), fp32 -> bf16
    short8 a0, a1;
    {
        const float* xr = x + (size_t)(s0 + m0 + ln) * 64 + qg * 8;
        a0 = pack_a(*(const f4*)xr, *(const f4*)(xr + 4));
        if (y) a1 = pack_a(*(const f4*)(xr + 32), *(const f4*)(xr + 36));
        else   a1 = a0;  // unused
    }

    int buf = 0;
    #pragma unroll 1
    for (int c = 0; c < 4; ++c) {
        const int gc = y * 4 + c;          // global chunk 0..7 = l in [8gc, 8gc+8)

        // ---- phase 1: MFMA 64 outcols for this wave's 16 samples ----
        #pragma unroll
        for (int nt = 0; nt < 4; ++nt) {
            int ncol = gc * 64 + nt * 16 + ln;
            const short8* bp8 = (const short8*)(Bp + ncol * 64 + qg * 8);
            f32x4 acc = {0.f, 0.f, 0.f, 0.f};
            acc = __builtin_amdgcn_mfma_f32_16x16x32_bf16(a0, bp8[0], acc, 0, 0, 0);
            if (y) acc = __builtin_amdgcn_mfma_f32_16x16x32_bf16(a1, bp8[4], acc, 0, 0, 0);
            float bias = (ncol < 504) ? b1[ncol] : 0.f;
            #pragma unroll
            for (int r = 0; r < 4; ++r) {
                float v = tanh_fast(acc[r] + bias);
                h1c[buf][(m0 + qg * 4 + r) * 72 + nt * 16 + ln] = to_bf16u(v);
            }
        }
        __syncthreads();   // h1 chunk ready (also covers xs staging on c==0)

        // ---- phase 2: layers 2,3 + spline, 2 dims per wave ----
        #pragma unroll 1
        for (int it = 0; it < 2; ++it) {
            int idx = wave * 2 + it;       // 0..7 within chunk
            int dd = (gc == 7 && idx == 7) ? 0 : gc * 8 + 1 + idx;
            dd = __builtin_amdgcn_readfirstlane(dd);

            float p[PP];
            if (dd == 0) {
                #pragma unroll
                for (int i = 0; i < PP; ++i) p[i] = init_param[i];
            } else {
                const int l = dd - 1;
                const int dl = l - gc * 8;         // 0..7
                uint4 hv = *(const uint4*)&h1c[buf][lane * 72 + dl * 8];
                float h1f[8];
                h1f[0] = __uint_as_float(hv.x << 16);
                h1f[1] = __uint_as_float(hv.x & 0xFFFF0000u);
                h1f[2] = __uint_as_float(hv.y << 16);
                h1f[3] = __uint_as_float(hv.y & 0xFFFF0000u);
                h1f[4] = __uint_as_float(hv.z << 16);
                h1f[5] = __uint_as_float(hv.z & 0xFFFF0000u);
                h1f[6] = __uint_as_float(hv.w << 16);
                h1f[7] = __uint_as_float(hv.w & 0xFFFF0000u);

                float h2[8];
                #pragma unroll
                for (int g = 0; g < 8; ++g) h2[g] = b2[l * 8 + g];
                #pragma unroll
                for (int h = 0; h < 8; ++h) {
                    #pragma unroll
                    for (int g = 0; g < 8; ++g)
                        h2[g] = fmaf(h1f[h], W2[l * 64 + h * 8 + g], h2[g]);
                }
                #pragma unroll
                for (int g = 0; g < 8; ++g) h2[g] = tanh_fast(h2[g]);

                #pragma unroll
                for (int q = 0; q < PP; ++q) p[q] = b3[l * PP + q];
                #pragma unroll
                for (int g = 0; g < 8; ++g) {
                    #pragma unroll
                    for (int q = 0; q < PP; ++q)
                        p[q] = fmaf(h2[g], W3[(l * 8 + g) * PP + q], p[q]);
                }
            }

            // ---- rational quadratic spline (round-2/4 validated) ----
            const float xf = xs[lane * 65 + dd];

            float wmax = p[0];
            #pragma unroll
            for (int i = 1; i < KK; ++i) wmax = fmaxf(wmax, p[i]);
            float we[KK]; float wsum = 0.f;
            #pragma unroll
            for (int i = 0; i < KK; ++i) { we[i] = exp_fast(p[i] - wmax); wsum += we[i]; }
            const float wnorm = (1.0f - MIN_Wc * KK) * rcp_fast(wsum);
            float cumw[KK + 1], wdt[KK];
            cumw[0] = -Bc;
            float acw = 0.f;
            #pragma unroll
            for (int i = 0; i < KK; ++i) { acw += MIN_Wc + wnorm * we[i]; cumw[i + 1] = 2.f * Bc * acw - Bc; }
            cumw[KK] = Bc;
            #pragma unroll
            for (int i = 0; i < KK; ++i) wdt[i] = cumw[i + 1] - cumw[i];

            float hmax = p[KK];
            #pragma unroll
            for (int i = 1; i < KK; ++i) hmax = fmaxf(hmax, p[KK + i]);
            float he[KK]; float hsum = 0.f;
            #pragma unroll
            for (int i = 0; i < KK; ++i) { he[i] = exp_fast(p[KK + i] - hmax); hsum += he[i]; }
            const float hnorm = (1.0f - MIN_Hc * KK) * rcp_fast(hsum);
            float cumh[KK + 1], hgt[KK];
            cumh[0] = -Bc;
            float ach = 0.f;
            #pragma unroll
            for (int i = 0; i < KK; ++i) { ach += MIN_Hc + hnorm * he[i]; cumh[i + 1] = 2.f * Bc * ach - Bc; }
            cumh[KK] = Bc;
            #pragma unroll
            for (int i = 0; i < KK; ++i) hgt[i] = cumh[i + 1] - cumh[i];

            float derivs[KK + 1];
            derivs[0] = 1.0f;
            derivs[KK] = 1.0f;
            #pragma unroll
            for (int i = 0; i < KK - 1; ++i) derivs[i + 1] = MIN_Dc + softplus_fast(p[2 * KK + i]);

            const float xc = fminf(fmaxf(xf, -Bc), Bc);

            float icw = cumw[0], ibw = wdt[0], ich = cumh[0], ih = hgt[0];
            float idv = derivs[0], idvp1 = derivs[1];
            #pragma unroll
            for (int i = 1; i < KK; ++i) {
                bool cc = xc >= cumw[i];
                icw   = cc ? cumw[i]       : icw;
                ibw   = cc ? wdt[i]        : ibw;
                ich   = cc ? cumh[i]       : ich;
                ih    = cc ? hgt[i]        : ih;
                idv   = cc ? derivs[i]     : idv;
                idvp1 = cc ? derivs[i + 1] : idvp1;
            }

            const float ibw_r = rcp_fast(ibw);
            const float idl = ih * ibw_r;
            const float theta = (xc - icw) * ibw_r;
            const float omt = 1.0f - theta;
            const float tmt = theta * omt;
            const float num = ih * (idl * theta * theta + idv * tmt);
            const float den = idl + (idv + idvp1 - 2.0f * idl) * tmt;
            const float outv = ich + num * rcp_fast(den);
            const float dnum = idl * idl * (idvp1 * theta * theta + 2.0f * idl * tmt + idv * omt * omt);
            const float ld = log_fast(dnum) - 2.0f * log_fast(den);

            const bool inside = (xf >= -Bc) && (xf <= Bc);
            const float z = inside ? outv : xf;
            float ldv = inside ? ld : 0.0f;

            out[dd * NN + s0 + lane] = z;   // coalesced

            #pragma unroll
            for (int off = 32; off > 0; off >>= 1) ldv += __shfl_down(ldv, off);
            if (lane == 0) out[NN * DD + dd * (NN / 64) + blockIdx.x] = ldv;
        }
        buf ^= 1;   // WAR-safe: one barrier/chunk suffices with double buffer
    }
}

extern "C" void kernel_launch(void* const* d_in, const int* in_sizes, int n_in,
                              void* d_out, int out_size, void* d_ws, size_t ws_size,
                              hipStream_t stream) {
    const float* x          = (const float*)d_in[0];
    const float* init_param = (const float*)d_in[1];
    const float* W1         = (const float*)d_in[2];
    const float* b1         = (const float*)d_in[3];
    const float* W2         = (const float*)d_in[4];
    const float* b2         = (const float*)d_in[5];
    const float* W3         = (const float*)d_in[6];
    const float* b3         = (const float*)d_in[7];
    float* out = (float*)d_out;

    ushort* Bp = (ushort*)d_ws;            // 512*64 bf16 = 64 KB

    pack_b1<<<128, 256, 0, stream>>>(W1, Bp);
    fused_kernel<<<dim3(512, 2), 256, 0, stream>>>(x, init_param, Bp, b1,
                                                   W2, b2, W3, b3, out);
}

// Round 6
// 116.240 us; speedup vs baseline: 1.5396x; 1.0075x over previous
//
#include <hip/hip_runtime.h>
#include <hip/hip_bf16.h>
#include <math.h>

#define KK 5
#define Bc 5.0f
#define NN 32768
#define DD 64
#define LL 63
#define PP 14
#define MIN_Wc 0.001f
#define MIN_Hc 0.001f
#define MIN_Dc 0.001f

typedef float f4 __attribute__((ext_vector_type(4)));
typedef float f32x4 __attribute__((ext_vector_type(4)));
typedef short short8 __attribute__((ext_vector_type(8)));

__device__ __forceinline__ float rcp_fast(float v)  { return __builtin_amdgcn_rcpf(v); }
__device__ __forceinline__ float exp_fast(float v)  { return __expf(v); }
__device__ __forceinline__ float log_fast(float v)  { return __logf(v); }
__device__ __forceinline__ float tanh_fast(float v) {
    float e = exp_fast(2.0f * v);                 // overflow->inf->rcp->0->1: correct
    return 1.0f - 2.0f * rcp_fast(e + 1.0f);
}
__device__ __forceinline__ float softplus_fast(float v) {
    return (v > 15.0f) ? v : log_fast(1.0f + exp_fast(v));
}
__device__ __forceinline__ ushort to_bf16u(float v) {
    __hip_bfloat16 b = __float2bfloat16(v);
    return *(ushort*)&b;
}

// ---------------- kernel 0: pack W1 fp32 -> bf16 B[512][64] (n-major) -------
// B[n][k] = W1[l=n>>3, j=k, h=n&7] for n<504,k<63 else 0. W1 arrives pre-masked.
__global__ __launch_bounds__(256) void pack_b1(const float* __restrict__ W1,
                                               ushort* __restrict__ Bp) {
    int id = blockIdx.x * 256 + threadIdx.x;     // 0..32767
    int n = id >> 6, k = id & 63;
    float v = 0.f;
    if (n < 504 && k < 63) {
        int l = n >> 3, h = n & 7;
        v = W1[(l * 63 + k) * 8 + h];
    }
    Bp[id] = to_bf16u(v);
}

__device__ __forceinline__ short8 pack_a(f4 v0, f4 v1) {
    short8 a;
    a[0] = (short)to_bf16u(v0.x); a[1] = (short)to_bf16u(v0.y);
    a[2] = (short)to_bf16u(v0.z); a[3] = (short)to_bf16u(v0.w);
    a[4] = (short)to_bf16u(v1.x); a[5] = (short)to_bf16u(v1.y);
    a[6] = (short)to_bf16u(v1.z); a[7] = (short)to_bf16u(v1.w);
    return a;
}

// ---------------- fused kernel -----------------------------------------------
// grid (512, 4): x = 64-sample tile, y = 16-dim group.
//   y handles dims [16y+1 .. 16y+16]  (y==3: idx 15 is dim 0 / init_param).
//   causality: y<2 -> l<32 -> only k<32 contributes (W1 pre-masked) -> 1 MFMA.
// LDS = h1 only (17.4 KB), ONE barrier. 2048 blocks -> 8 blocks/CU.
#define H1S 136   // u16 row stride: 272B = 68 banks = 4 mod 32 (same residue as proven 72)
__global__ __launch_bounds__(256, 8) void fused_kernel(
    const float* __restrict__ x, const float* __restrict__ init_param,
    const ushort* __restrict__ Bp, const float* __restrict__ b1,
    const float* __restrict__ W2, const float* __restrict__ b2,
    const float* __restrict__ W3, const float* __restrict__ b3,
    float* __restrict__ out)
{
    __shared__ ushort h1c[64 * H1S];   // [sample][128 outcols], bf16
    const int tid = threadIdx.x;
    const int s0 = blockIdx.x * 64;
    const int y  = blockIdx.y;
    const int lane = tid & 63;
    const int wave = __builtin_amdgcn_readfirstlane(tid >> 6);
    const int ln = lane & 15, qg = lane >> 4;
    const int m0 = wave * 16;

    // prefetch spline x values (per-lane gather, hidden behind phase 1)
    float xv[4];
    #pragma unroll
    for (int it = 0; it < 4; ++it) {
        int idx = wave * 4 + it;
        int dd = (y == 3 && idx == 15) ? 0 : y * 16 + 1 + idx;
        xv[it] = x[(size_t)(s0 + lane) * 64 + dd];
    }

    // A-fragments (fp32 -> bf16), verified layout: A[m=ln][k=qg*8+j]
    short8 a0, a1;
    {
        const float* xr = x + (size_t)(s0 + m0 + ln) * 64 + qg * 8;
        a0 = pack_a(*(const f4*)xr, *(const f4*)(xr + 4));
        a1 = (y >= 2) ? pack_a(*(const f4*)(xr + 32), *(const f4*)(xr + 36)) : a0;
    }

    // ---- phase 1: MFMA all 128 outcols for this wave's 16 samples ----
    #pragma unroll
    for (int nt = 0; nt < 8; ++nt) {
        int ncol = y * 128 + nt * 16 + ln;
        const short8* bp8 = (const short8*)(Bp + ncol * 64 + qg * 8);
        f32x4 acc = {0.f, 0.f, 0.f, 0.f};
        acc = __builtin_amdgcn_mfma_f32_16x16x32_bf16(a0, bp8[0], acc, 0, 0, 0);
        if (y >= 2)
            acc = __builtin_amdgcn_mfma_f32_16x16x32_bf16(a1, bp8[4], acc, 0, 0, 0);
        float bias = (ncol < 504) ? b1[ncol] : 0.f;
        #pragma unroll
        for (int r = 0; r < 4; ++r) {
            float v = tanh_fast(acc[r] + bias);
            h1c[(m0 + qg * 4 + r) * H1S + nt * 16 + ln] = to_bf16u(v);
        }
    }
    __syncthreads();   // the only barrier

    // ---- phase 2: layers 2,3 + spline, 4 dims per wave ----
    #pragma unroll 1
    for (int it = 0; it < 4; ++it) {
        int idx = wave * 4 + it;
        int dd = (y == 3 && idx == 15) ? 0 : y * 16 + 1 + idx;
        dd = __builtin_amdgcn_readfirstlane(dd);
        const float xf = xv[it];

        float p[PP];
        if (dd == 0) {
            #pragma unroll
            for (int i = 0; i < PP; ++i) p[i] = init_param[i];
        } else {
            const int l = dd - 1;
            const int dl = l - y * 16;           // 0..15
            uint4 hv = *(const uint4*)&h1c[lane * H1S + dl * 8];
            float h1f[8];
            h1f[0] = __uint_as_float(hv.x << 16);
            h1f[1] = __uint_as_float(hv.x & 0xFFFF0000u);
            h1f[2] = __uint_as_float(hv.y << 16);
            h1f[3] = __uint_as_float(hv.y & 0xFFFF0000u);
            h1f[4] = __uint_as_float(hv.z << 16);
            h1f[5] = __uint_as_float(hv.z & 0xFFFF0000u);
            h1f[6] = __uint_as_float(hv.w << 16);
            h1f[7] = __uint_as_float(hv.w & 0xFFFF0000u);

            float h2[8];
            #pragma unroll
            for (int g = 0; g < 8; ++g) h2[g] = b2[l * 8 + g];
            #pragma unroll
            for (int h = 0; h < 8; ++h) {
                #pragma unroll
                for (int g = 0; g < 8; ++g)
                    h2[g] = fmaf(h1f[h], W2[l * 64 + h * 8 + g], h2[g]);
            }
            #pragma unroll
            for (int g = 0; g < 8; ++g) h2[g] = tanh_fast(h2[g]);

            #pragma unroll
            for (int q = 0; q < PP; ++q) p[q] = b3[l * PP + q];
            #pragma unroll
            for (int g = 0; g < 8; ++g) {
                #pragma unroll
                for (int q = 0; q < PP; ++q)
                    p[q] = fmaf(h2[g], W3[(l * 8 + g) * PP + q], p[q]);
            }
        }

        // ---- rational quadratic spline (validated since round 2) ----
        float wmax = p[0];
        #pragma unroll
        for (int i = 1; i < KK; ++i) wmax = fmaxf(wmax, p[i]);
        float we[KK]; float wsum = 0.f;
        #pragma unroll
        for (int i = 0; i < KK; ++i) { we[i] = exp_fast(p[i] - wmax); wsum += we[i]; }
        const float wnorm = (1.0f - MIN_Wc * KK) * rcp_fast(wsum);
        float cumw[KK + 1], wdt[KK];
        cumw[0] = -Bc;
        float acw = 0.f;
        #pragma unroll
        for (int i = 0; i < KK; ++i) { acw += MIN_Wc + wnorm * we[i]; cumw[i + 1] = 2.f * Bc * acw - Bc; }
        cumw[KK] = Bc;
        #pragma unroll
        for (int i = 0; i < KK; ++i) wdt[i] = cumw[i + 1] - cumw[i];

        float hmax = p[KK];
        #pragma unroll
        for (int i = 1; i < KK; ++i) hmax = fmaxf(hmax, p[KK + i]);
        float he[KK]; float hsum = 0.f;
        #pragma unroll
        for (int i = 0; i < KK; ++i) { he[i] = exp_fast(p[KK + i] - hmax); hsum += he[i]; }
        const float hnorm = (1.0f - MIN_Hc * KK) * rcp_fast(hsum);
        float cumh[KK + 1], hgt[KK];
        cumh[0] = -Bc;
        float ach = 0.f;
        #pragma unroll
        for (int i = 0; i < KK; ++i) { ach += MIN_Hc + hnorm * he[i]; cumh[i + 1] = 2.f * Bc * ach - Bc; }
        cumh[KK] = Bc;
        #pragma unroll
        for (int i = 0; i < KK; ++i) hgt[i] = cumh[i + 1] - cumh[i];

        float derivs[KK + 1];
        derivs[0] = 1.0f;
        derivs[KK] = 1.0f;
        #pragma unroll
        for (int i = 0; i < KK - 1; ++i) derivs[i + 1] = MIN_Dc + softplus_fast(p[2 * KK + i]);

        const float xc = fminf(fmaxf(xf, -Bc), Bc);

        float icw = cumw[0], ibw = wdt[0], ich = cumh[0], ih = hgt[0];
        float idv = derivs[0], idvp1 = derivs[1];
        #pragma unroll
        for (int i = 1; i < KK; ++i) {
            bool cc = xc >= cumw[i];
            icw   = cc ? cumw[i]       : icw;
            ibw   = cc ? wdt[i]        : ibw;
            ich   = cc ? cumh[i]       : ich;
            ih    = cc ? hgt[i]        : ih;
            idv   = cc ? derivs[i]     : idv;
            idvp1 = cc ? derivs[i + 1] : idvp1;
        }

        const float ibw_r = rcp_fast(ibw);
        const float idl = ih * ibw_r;
        const float theta = (xc - icw) * ibw_r;
        const float omt = 1.0f - theta;
        const float tmt = theta * omt;
        const float num = ih * (idl * theta * theta + idv * tmt);
        const float den = idl + (idv + idvp1 - 2.0f * idl) * tmt;
        const float outv = ich + num * rcp_fast(den);
        const float dnum = idl * idl * (idvp1 * theta * theta + 2.0f * idl * tmt + idv * omt * omt);
        const float ld = log_fast(dnum) - 2.0f * log_fast(den);

        const bool inside = (xf >= -Bc) && (xf <= Bc);
        const float z = inside ? outv : xf;
        float ldv = inside ? ld : 0.0f;

        out[dd * NN + s0 + lane] = z;   // coalesced

        #pragma unroll
        for (int off = 32; off > 0; off >>= 1) ldv += __shfl_down(ldv, off);
        if (lane == 0) out[NN * DD + dd * (NN / 64) + blockIdx.x] = ldv;
    }
}

extern "C" void kernel_launch(void* const* d_in, const int* in_sizes, int n_in,
                              void* d_out, int out_size, void* d_ws, size_t ws_size,
                              hipStream_t stream) {
    const float* x          = (const float*)d_in[0];
    const float* init_param = (const float*)d_in[1];
    const float* W1         = (const float*)d_in[2];
    const float* b1         = (const float*)d_in[3];
    const float* W2         = (const float*)d_in[4];
    const float* b2         = (const float*)d_in[5];
    const float* W3         = (const float*)d_in[6];
    const float* b3         = (const float*)d_in[7];
    float* out = (float*)d_out;

    ushort* Bp = (ushort*)d_ws;            // 512*64 bf16 = 64 KB

    pack_b1<<<128, 256, 0, stream>>>(W1, Bp);
    fused_kernel<<<dim3(512, 4), 256, 0, stream>>>(x, init_param, Bp, b1,
                                                   W2, b2, W3, b3, out);
}